// Round 11
// baseline (599.724 us; speedup 1.0000x reference)
//
#include <hip/hip_runtime.h>
#include <hip/hip_fp16.h>

#define FEAT 128
#define CHUNK 8192    // edges per sort chunk
#define BSH 7         // 128-node buckets
#define CAP 6144      // per-bucket col capacity (mean 4096, sigma ~64)
#define RSTRIDE 784   // runs-table row stride (783 used: 782 offsets + cnt)

typedef _Float16 half8 __attribute__((ext_vector_type(8)));
typedef float floatx4 __attribute__((ext_vector_type(4)));

// ---------------- CSR build: 2 dispatches, zero global atomics ----------------

// Dispatch 1 (fused): blocks [0,nchunks) bucket-sort their edge chunk in place
// (pairs stay chunk-major, packed src | (dst&127)<<24) and write a per-chunk
// run-offset table; blocks [nchunks, nchunks+24) pre-pack W1..W3.
__global__ __launch_bounds__(256) void sort_prep_kernel(
    const int* __restrict__ ei, int E, int nchunks, int nbuk,
    int* __restrict__ pairs, int* __restrict__ runs,
    const float* __restrict__ W1, const float* __restrict__ W2,
    const float* __restrict__ W3, _Float16* __restrict__ P1,
    _Float16* __restrict__ P2, _Float16* __restrict__ P3) {
  __shared__ int lhist[1024];
  __shared__ int lofs[1024];
  __shared__ int lcur[1024];
  __shared__ int tsum[256];
  __shared__ int stage[CHUNK];
  int t = threadIdx.x;
  if ((int)blockIdx.x >= nchunks) {
    // ---- weight pre-pack path ----
    int b = blockIdx.x - nchunks;
    const float* W = (b < 8) ? W1 : (b < 16) ? W2 : W3;
    _Float16* P = (b < 8) ? P1 : (b < 16) ? P2 : P3;
    int e = (b & 7) * 256 + t;
    int l = e & 63;
    int ks = (e >> 6) & 3;
    int tn = e >> 8;
    int n = tn * 16 + (l & 15);
    int k0 = ks * 32 + (l >> 4) * 8;
    half8 v;
#pragma unroll
    for (int j = 0; j < 8; ++j) v[j] = (_Float16)W[(k0 + j) * 128 + n];
    *(half8*)(P + (size_t)e * 8) = v;
    return;
  }
  // ---- chunk sort path ----
  int c = blockIdx.x;
  int e0 = c * CHUNK;
  int e1 = e0 + CHUNK; if (e1 > E) e1 = E;
  int cnt = e1 - e0;
#pragma unroll
  for (int u = 0; u < 4; ++u) lhist[t + u * 256] = 0;
  __syncthreads();
  for (int j = e0 + t; j < e1; j += 256) atomicAdd(&lhist[ei[E + j] >> BSH], 1);
  __syncthreads();
  // scan 1024 slots: 4 per thread + 256-wide Hillis-Steele over thread sums
  int a0 = lhist[4 * t], a1 = lhist[4 * t + 1];
  int a2 = lhist[4 * t + 2], a3 = lhist[4 * t + 3];
  int s = ((a0 + a1) + (a2 + a3));
  tsum[t] = s;
  __syncthreads();
  for (int o = 1; o < 256; o <<= 1) {
    int x = (t >= o) ? tsum[t - o] : 0;
    __syncthreads();
    tsum[t] += x;
    __syncthreads();
  }
  int base = tsum[t] - s;  // exclusive
  lofs[4 * t] = base;       lcur[4 * t] = base;
  lofs[4 * t + 1] = base + a0;           lcur[4 * t + 1] = base + a0;
  lofs[4 * t + 2] = base + a0 + a1;      lcur[4 * t + 2] = base + a0 + a1;
  lofs[4 * t + 3] = base + a0 + a1 + a2; lcur[4 * t + 3] = base + a0 + a1 + a2;
  __syncthreads();
  for (int k = t; k < nbuk; k += 256) runs[(size_t)c * RSTRIDE + k] = lofs[k];
  if (t == 0) runs[(size_t)c * RSTRIDE + nbuk] = cnt;
  for (int j = e0 + t; j < e1; j += 256) {
    int sv = ei[j];
    int d = ei[E + j];
    int p = atomicAdd(&lcur[d >> BSH], 1);
    stage[p] = sv | ((d & 127) << 24);
  }
  __syncthreads();
  for (int j = t; j < cnt; j += 256) pairs[e0 + j] = stage[j];
}

// Dispatch 2: block b (one per 128-node bucket) gathers its (bucket,chunk)
// runs, builds row_se / dis / node-ranked col (byte offsets src*256).
__global__ __launch_bounds__(256) void bucket_csr_kernel(
    const int* __restrict__ pairs, const int* __restrict__ runs, int nchunks,
    int nbuk, int2* __restrict__ row_se, float* __restrict__ dis,
    int* __restrict__ col, int N) {
  __shared__ int rs[512], rl[512], ro[512];
  __shared__ int cnt[128], sc[128];
  __shared__ int stage[CAP];
  int b = blockIdx.x, t = threadIdx.x;
  for (int c = t; c < 512; c += 256) {
    int s0 = 0, len = 0;
    if (c < nchunks) {
      const int* rr = runs + (size_t)c * RSTRIDE;
      s0 = rr[b];
      len = rr[b + 1] - s0;
    }
    rs[c] = s0; rl[c] = len;
  }
  if (t < 128) cnt[t] = 0;
  __syncthreads();
  // exclusive scan rl -> ro (512 slots)
  ro[t] = rl[t]; ro[t + 256] = rl[t + 256];
  __syncthreads();
  for (int o = 1; o < 512; o <<= 1) {
    int v0 = (t >= o) ? ro[t - o] : 0;
    int v1 = (t + 256 >= o) ? ro[t + 256 - o] : 0;
    __syncthreads();
    ro[t] += v0; ro[t + 256] += v1;
    __syncthreads();
  }
  int ce = ro[511];
  int y0 = ro[t] - rl[t];
  int y1 = ro[t + 256] - rl[t + 256];
  __syncthreads();
  ro[t] = y0; ro[t + 256] = y1;
  __syncthreads();
  int colbase = b * CAP;
  bool fits = ce <= CAP;
  if (fits) {
    for (int c = t; c < nchunks; c += 256) {
      int gs = c * CHUNK + rs[c];
      int base = ro[c];
      int len = rl[c];
      for (int j = 0; j < len; ++j) {
        int p = pairs[gs + j];
        stage[base + j] = p;
        atomicAdd(&cnt[((unsigned)p) >> 24], 1);
      }
    }
  } else {  // statistically unreachable guard
    for (int c = t; c < nchunks; c += 256) {
      int gs = c * CHUNK + rs[c];
      for (int j = 0; j < rl[c]; ++j)
        atomicAdd(&cnt[((unsigned)pairs[gs + j]) >> 24], 1);
    }
  }
  __syncthreads();
  int v = 0, excl = 0;
  if (t < 128) { v = cnt[t]; sc[t] = v; }
  __syncthreads();
  for (int o = 1; o < 128; o <<= 1) {
    int x = (t >= o && t < 128) ? sc[t - o] : 0;
    __syncthreads();
    if (t < 128) sc[t] += x;
    __syncthreads();
  }
  if (t < 128) {
    excl = sc[t] - v;
    int node = b * 128 + t;
    if (node < N) {
      row_se[node] = make_int2(colbase + excl, colbase + excl + v);
      dis[node] = rsqrtf((float)(v + 1));  // +1 self-loop
    }
    cnt[t] = excl;  // reuse as cursor
  }
  __syncthreads();
  if (fits) {
    for (int j = t; j < ce; j += 256) {
      int p = stage[j];
      int loc = atomicAdd(&cnt[((unsigned)p) >> 24], 1);
      col[colbase + loc] = (p & 0xFFFFFF) << 8;  // byte offset: src * 256
    }
  } else {
    for (int c = t; c < nchunks; c += 256) {
      int gs = c * CHUNK + rs[c];
      for (int j = 0; j < rl[c]; ++j) {
        int p = pairs[gs + j];
        int loc = atomicAdd(&cnt[((unsigned)p) >> 24], 1);
        if (loc < CAP) col[colbase + loc] = (p & 0xFFFFFF) << 8;
      }
    }
  }
}

// ---------------- dense / fused kernels ----------------

// h1 = (X @ W1) * dis[row], fp32 in, fp16 out. MFMA swapped-operand form:
// D = W^T (A-op, m=feature) x X^T (B-op, n=node); lane stores 4 consecutive
// features of one node per tile.
__global__ __launch_bounds__(256) void mm1_kernel(
    const float* __restrict__ Av, const _Float16* __restrict__ Wpk,
    const float* __restrict__ scale, __half* __restrict__ C, int N) {
  int t = threadIdx.x;
  int wave = t >> 6, lane = t & 63;
  int quad = lane >> 4, nidx = lane & 15;
  int m0 = blockIdx.x * 64 + wave * 16;
  int arow = m0 + nidx;
  bool avalid = arow < N;
  floatx4 acc[8];
#pragma unroll
  for (int tn = 0; tn < 8; ++tn) acc[tn] = (floatx4){0.f, 0.f, 0.f, 0.f};
#pragma unroll
  for (int ks = 0; ks < 4; ++ks) {
    half8 x = {};
    if (avalid) {
      const float* p = Av + (size_t)arow * 128 + ks * 32 + quad * 8;
      float4 f0 = *(const float4*)p;
      float4 f1 = *(const float4*)(p + 4);
      x[0] = (_Float16)f0.x; x[1] = (_Float16)f0.y;
      x[2] = (_Float16)f0.z; x[3] = (_Float16)f0.w;
      x[4] = (_Float16)f1.x; x[5] = (_Float16)f1.y;
      x[6] = (_Float16)f1.z; x[7] = (_Float16)f1.w;
    }
#pragma unroll
    for (int tn = 0; tn < 8; ++tn) {
      half8 wfrag = *(const half8*)(Wpk + ((size_t)((tn * 4 + ks) * 64 + lane)) * 8);
      acc[tn] = __builtin_amdgcn_mfma_f32_16x16x32_f16(wfrag, x, acc[tn], 0, 0, 0);
    }
  }
  if (avalid) {
    float s = scale[arow];
#pragma unroll
    for (int tn = 0; tn < 8; ++tn) {
      union { uint2 u; __half2 h[2]; } st;
      st.h[0] = __floats2half2_rn(acc[tn][0] * s, acc[tn][1] * s);
      st.h[1] = __floats2half2_rn(acc[tn][2] * s, acc[tn][3] * s);
      *(uint2*)(C + (size_t)arow * 128 + tn * 16 + quad * 4) = st.u;
    }
  }
}

// Fused layer kernel, WAVE-LOCAL: each wave owns 4 nodes. Gather relu'd rows
// into the wave's private LDS slice (no __syncthreads anywhere), then run the
// next layer's MFMAs using 4 of 16 B-columns (garbage columns never stored;
// matmul columns are independent). x-frags held in regs: 4 LDS reads/wave.
__global__ __launch_bounds__(256) void agg_fuse_kernel(
    const __half* __restrict__ hs_in, const int2* __restrict__ row_se,
    const int* __restrict__ col, const float* __restrict__ dis,
    const float* __restrict__ bias, const _Float16* __restrict__ Wpk,
    __half* __restrict__ hs_out, int N) {
  __shared__ _Float16 Xs[4][4][136];  // [wave][local node][feat], wave-private
  int t = threadIdx.x;
  int wave = t >> 6, lane = t & 63;
  int n0 = blockIdx.x * 16 + wave * 4;
  const char* hb = (const char*)hs_in + lane * 4;  // lane's half2 within a row
  float2 b2 = ((const float2*)bias)[lane];
  for (int s = 0; s < 4; ++s) {
    int node = n0 + s;
    float ox = 0.f, oy = 0.f;
    if (node < N) {
      float2 selfv = __half22float2(*(const __half2*)(hb + ((size_t)node << 8)));
      float ax = selfv.x, ay = selfv.y;
      int2 se = row_se[node];
      int i = se.x, e = se.y;
      for (; i + 16 <= e; i += 16) {
        float2 v[16];
#pragma unroll
        for (int u = 0; u < 16; ++u)
          v[u] = __half22float2(*(const __half2*)(hb + col[i + u]));
        float bx = 0.f, by = 0.f;
#pragma unroll
        for (int u = 0; u < 16; ++u) { bx += v[u].x; by += v[u].y; }
        ax += bx; ay += by;
      }
      for (; i + 4 <= e; i += 4) {
        float2 v0 = __half22float2(*(const __half2*)(hb + col[i + 0]));
        float2 v1 = __half22float2(*(const __half2*)(hb + col[i + 1]));
        float2 v2 = __half22float2(*(const __half2*)(hb + col[i + 2]));
        float2 v3 = __half22float2(*(const __half2*)(hb + col[i + 3]));
        ax += (v0.x + v1.x) + (v2.x + v3.x);
        ay += (v0.y + v1.y) + (v2.y + v3.y);
      }
      for (; i < e; ++i) {
        float2 v = __half22float2(*(const __half2*)(hb + col[i]));
        ax += v.x; ay += v.y;
      }
      float d = dis[node];
      ox = fmaxf(fmaf(d, ax, b2.x), 0.f);
      oy = fmaxf(fmaf(d, ay, b2.y), 0.f);
    }
    *(__half2*)&Xs[wave][s][2 * lane] = __floats2half2_rn(ox, oy);
  }
  // wave-internal LDS ordering (lgkmcnt) guarantees visibility; no barrier.
  int quad = lane >> 4, nidx = lane & 15;
  half8 xf[4];
#pragma unroll
  for (int ks = 0; ks < 4; ++ks)
    xf[ks] = *(const half8*)&Xs[wave][nidx & 3][ks * 32 + quad * 8];
  int node = n0 + nidx;                // valid only for nidx < 4
  bool store = (nidx < 4) && (node < N);
  float sc = store ? dis[node] : 0.f;
#pragma unroll
  for (int tn = 0; tn < 8; ++tn) {
    floatx4 acc = (floatx4){0.f, 0.f, 0.f, 0.f};
#pragma unroll
    for (int ks = 0; ks < 4; ++ks) {
      half8 w = *(const half8*)(Wpk + ((size_t)((tn * 4 + ks) * 64 + lane)) * 8);
      acc = __builtin_amdgcn_mfma_f32_16x16x32_f16(w, xf[ks], acc, 0, 0, 0);
    }
    if (store) {
      union { uint2 u; __half2 h[2]; } st;
      st.h[0] = __floats2half2_rn(acc[0] * sc, acc[1] * sc);
      st.h[1] = __floats2half2_rn(acc[2] * sc, acc[3] * sc);
      *(uint2*)(hs_out + (size_t)node * 128 + tn * 16 + quad * 4) = st.u;
    }
  }
}

// Standalone layer-3 aggregation (no following matmul).
__global__ __launch_bounds__(256) void agg_kernel(
    const __half* __restrict__ hs, const int2* __restrict__ row_se,
    const int* __restrict__ col, const float* __restrict__ dis,
    const float* __restrict__ bias, __half* __restrict__ out, int N) {
  int node = blockIdx.x * 4 + (threadIdx.x >> 6);
  int lane = threadIdx.x & 63;
  if (node >= N) return;
  const char* hb = (const char*)hs + lane * 4;
  float2 selfv = __half22float2(*(const __half2*)(hb + ((size_t)node << 8)));
  float ax = selfv.x, ay = selfv.y;
  int2 se = row_se[node];
  int i = se.x, e = se.y;
  for (; i + 16 <= e; i += 16) {
    float2 v[16];
#pragma unroll
    for (int u = 0; u < 16; ++u) v[u] = __half22float2(*(const __half2*)(hb + col[i + u]));
    float bx = 0.f, by = 0.f;
#pragma unroll
    for (int u = 0; u < 16; ++u) { bx += v[u].x; by += v[u].y; }
    ax += bx; ay += by;
  }
  for (; i + 4 <= e; i += 4) {
    float2 v0 = __half22float2(*(const __half2*)(hb + col[i + 0]));
    float2 v1 = __half22float2(*(const __half2*)(hb + col[i + 1]));
    float2 v2 = __half22float2(*(const __half2*)(hb + col[i + 2]));
    float2 v3 = __half22float2(*(const __half2*)(hb + col[i + 3]));
    ax += (v0.x + v1.x) + (v2.x + v3.x);
    ay += (v0.y + v1.y) + (v2.y + v3.y);
  }
  for (; i < e; ++i) {
    float2 v = __half22float2(*(const __half2*)(hb + col[i]));
    ax += v.x; ay += v.y;
  }
  float d = dis[node];
  float2 b2 = ((const float2*)bias)[lane];
  float ox = fmaxf(fmaf(d, ax, b2.x), 0.f);
  float oy = fmaxf(fmaf(d, ay, b2.y), 0.f);
  ((__half2*)out)[(size_t)node * 64 + lane] = __floats2half2_rn(ox, oy);
}

// Fused head: mean pool (batch sorted -> binary search) + lin1+relu + lin2.
__global__ __launch_bounds__(128) void head_kernel(
    const __half* __restrict__ h, const int* __restrict__ batch,
    const float* __restrict__ l1w, const float* __restrict__ l1b,
    const float* __restrict__ l2w, const float* __restrict__ l2b,
    float* __restrict__ out, int N, int C) {
  __shared__ float row[128];
  __shared__ float row2[128];
  int grp = blockIdx.x, t = threadIdx.x;
  int lo = 0, hi = N;
  while (lo < hi) { int m = (lo + hi) >> 1; if (batch[m] < grp) lo = m + 1; else hi = m; }
  int start = lo;
  hi = N;
  while (lo < hi) { int m = (lo + hi) >> 1; if (batch[m] <= grp) lo = m + 1; else hi = m; }
  int end = lo;
  float a0 = 0.f, a1 = 0.f, a2 = 0.f, a3 = 0.f;
  int i = start;
  for (; i + 4 <= end; i += 4) {
    a0 += __half2float(h[(size_t)i * 128 + t]);
    a1 += __half2float(h[(size_t)(i + 1) * 128 + t]);
    a2 += __half2float(h[(size_t)(i + 2) * 128 + t]);
    a3 += __half2float(h[(size_t)(i + 3) * 128 + t]);
  }
  for (; i < end; ++i) a0 += __half2float(h[(size_t)i * 128 + t]);
  float sum = (a0 + a1) + (a2 + a3);
  float cntf = (float)(end - start);
  row[t] = sum / fmaxf(cntf, 1.0f);
  __syncthreads();
  float acc = l1b[t];
#pragma unroll 8
  for (int k = 0; k < 128; ++k) acc = fmaf(row[k], l1w[k * 128 + t], acc);
  row2[t] = fmaxf(acc, 0.f);
  __syncthreads();
  if (t < C) {
    float a = l2b[t];
#pragma unroll 8
    for (int k = 0; k < 128; ++k) a = fmaf(row2[k], l2w[k * C + t], a);
    out[grp * C + t] = a;
  }
}

// ---------------- launch ----------------

extern "C" void kernel_launch(void* const* d_in, const int* in_sizes, int n_in,
                              void* d_out, int out_size, void* d_ws, size_t ws_size,
                              hipStream_t stream) {
  const float* x   = (const float*)d_in[0];
  const int*   ei  = (const int*)d_in[1];     // [2][E]: src row then dst row
  const int*   bat = (const int*)d_in[2];
  const float* W1  = (const float*)d_in[3];
  const float* b1  = (const float*)d_in[4];
  const float* W2  = (const float*)d_in[5];
  const float* b2  = (const float*)d_in[6];
  const float* W3  = (const float*)d_in[7];
  const float* b3  = (const float*)d_in[8];
  const float* l1w = (const float*)d_in[9];
  const float* l1b = (const float*)d_in[10];
  const float* l2w = (const float*)d_in[11];
  const float* l2b = (const float*)d_in[12];

  int N = in_sizes[2];
  int E = in_sizes[1] / 2;
  int C = in_sizes[12];
  int G = out_size / C;
  float* outp = (float*)d_out;

  char* wp = (char*)d_ws;
  auto alloc = [&](size_t bytes) -> void* {
    void* p = (void*)wp;
    wp += (bytes + 255) & ~(size_t)255;
    return p;
  };
  int nbuk    = (N + 127) / 128;            // 128-node buckets (<=1024)
  int nchunks = (E + CHUNK - 1) / CHUNK;    // sort chunks (<=512)

  float*    dis    = (float*)alloc((size_t)N * 4);
  int2*     row_se = (int2*)alloc((size_t)N * 8);
  int*      col    = (int*)alloc((size_t)nbuk * CAP * 4);
  int*      pairs  = (int*)alloc((size_t)nchunks * CHUNK * 4);
  int*      runs   = (int*)alloc((size_t)nchunks * RSTRIDE * 4);
  _Float16* Wpk1   = (_Float16*)alloc(16384 * 2);
  _Float16* Wpk2   = (_Float16*)alloc(16384 * 2);
  _Float16* Wpk3   = (_Float16*)alloc(16384 * 2);
  __half*   bufA   = (__half*)alloc((size_t)N * FEAT * 2);
  __half*   bufB   = (__half*)alloc((size_t)N * FEAT * 2);

  // CSR build (2 dispatches) + weight pre-pack (fused into the first)
  sort_prep_kernel<<<nchunks + 24, 256, 0, stream>>>(
      ei, E, nchunks, nbuk, pairs, runs, W1, W2, W3, Wpk1, Wpk2, Wpk3);
  bucket_csr_kernel<<<nbuk, 256, 0, stream>>>(pairs, runs, nchunks, nbuk,
                                              row_se, dis, col, N);

  int mmB = (N + 63) / 64;
  int fB  = (N + 15) / 16;
  int agB = (N + 3) / 4;

  mm1_kernel<<<mmB, 256, 0, stream>>>(x, Wpk1, dis, bufA, N);
  agg_fuse_kernel<<<fB, 256, 0, stream>>>(bufA, row_se, col, dis, b1,
                                          Wpk2, bufB, N);
  agg_fuse_kernel<<<fB, 256, 0, stream>>>(bufB, row_se, col, dis, b2,
                                          Wpk3, bufA, N);
  agg_kernel<<<agB, 256, 0, stream>>>(bufA, row_se, col, dis, b3, bufB, N);
  head_kernel<<<G, 128, 0, stream>>>(bufB, bat, l1w, l1b, l2w, l2b, outp, N, C);
}

// Round 12
// 591.337 us; speedup vs baseline: 1.0142x; 1.0142x over previous
//
#include <hip/hip_runtime.h>
#include <hip/hip_fp16.h>

#define FEAT 128
#define CHUNK 8192    // edges per sort chunk
#define BSH 7         // 128-node buckets
#define CAP 6144      // per-bucket col capacity (mean 4096, sigma ~64)
#define RSTRIDE 784   // runs-table row stride (783 used: 782 offsets + cnt)

typedef _Float16 half8 __attribute__((ext_vector_type(8)));
typedef float floatx4 __attribute__((ext_vector_type(4)));

// ---------------- CSR build: 2 dispatches, zero global atomics ----------------

// Dispatch 1 (fused): blocks [0,nchunks) bucket-sort their edge chunk in place
// (pairs stay chunk-major, packed src | (dst&127)<<24) and write a per-chunk
// run-offset table; blocks [nchunks, nchunks+24) pre-pack W1..W3.
__global__ __launch_bounds__(256) void sort_prep_kernel(
    const int* __restrict__ ei, int E, int nchunks, int nbuk,
    int* __restrict__ pairs, int* __restrict__ runs,
    const float* __restrict__ W1, const float* __restrict__ W2,
    const float* __restrict__ W3, _Float16* __restrict__ P1,
    _Float16* __restrict__ P2, _Float16* __restrict__ P3) {
  __shared__ int lhist[1024];
  __shared__ int lofs[1024];
  __shared__ int lcur[1024];
  __shared__ int tsum[256];
  __shared__ int stage[CHUNK];
  int t = threadIdx.x;
  if ((int)blockIdx.x >= nchunks) {
    // ---- weight pre-pack path ----
    int b = blockIdx.x - nchunks;
    const float* W = (b < 8) ? W1 : (b < 16) ? W2 : W3;
    _Float16* P = (b < 8) ? P1 : (b < 16) ? P2 : P3;
    int e = (b & 7) * 256 + t;
    int l = e & 63;
    int ks = (e >> 6) & 3;
    int tn = e >> 8;
    int n = tn * 16 + (l & 15);
    int k0 = ks * 32 + (l >> 4) * 8;
    half8 v;
#pragma unroll
    for (int j = 0; j < 8; ++j) v[j] = (_Float16)W[(k0 + j) * 128 + n];
    *(half8*)(P + (size_t)e * 8) = v;
    return;
  }
  // ---- chunk sort path ----
  int c = blockIdx.x;
  int e0 = c * CHUNK;
  int e1 = e0 + CHUNK; if (e1 > E) e1 = E;
  int cnt = e1 - e0;
#pragma unroll
  for (int u = 0; u < 4; ++u) lhist[t + u * 256] = 0;
  __syncthreads();
  for (int j = e0 + t; j < e1; j += 256) atomicAdd(&lhist[ei[E + j] >> BSH], 1);
  __syncthreads();
  // scan 1024 slots: 4 per thread + 256-wide Hillis-Steele over thread sums
  int a0 = lhist[4 * t], a1 = lhist[4 * t + 1];
  int a2 = lhist[4 * t + 2], a3 = lhist[4 * t + 3];
  int s = ((a0 + a1) + (a2 + a3));
  tsum[t] = s;
  __syncthreads();
  for (int o = 1; o < 256; o <<= 1) {
    int x = (t >= o) ? tsum[t - o] : 0;
    __syncthreads();
    tsum[t] += x;
    __syncthreads();
  }
  int base = tsum[t] - s;  // exclusive
  lofs[4 * t] = base;       lcur[4 * t] = base;
  lofs[4 * t + 1] = base + a0;           lcur[4 * t + 1] = base + a0;
  lofs[4 * t + 2] = base + a0 + a1;      lcur[4 * t + 2] = base + a0 + a1;
  lofs[4 * t + 3] = base + a0 + a1 + a2; lcur[4 * t + 3] = base + a0 + a1 + a2;
  __syncthreads();
  for (int k = t; k < nbuk; k += 256) runs[(size_t)c * RSTRIDE + k] = lofs[k];
  if (t == 0) runs[(size_t)c * RSTRIDE + nbuk] = cnt;
  for (int j = e0 + t; j < e1; j += 256) {
    int sv = ei[j];
    int d = ei[E + j];
    int p = atomicAdd(&lcur[d >> BSH], 1);
    stage[p] = sv | ((d & 127) << 24);
  }
  __syncthreads();
  for (int j = t; j < cnt; j += 256) pairs[e0 + j] = stage[j];
}

// Dispatch 2: block b (one per 128-node bucket) gathers its (bucket,chunk)
// runs, builds row_se / dis / node-ranked col (byte offsets src*256).
__global__ __launch_bounds__(256) void bucket_csr_kernel(
    const int* __restrict__ pairs, const int* __restrict__ runs, int nchunks,
    int nbuk, int2* __restrict__ row_se, float* __restrict__ dis,
    int* __restrict__ col, int N) {
  __shared__ int rs[512], rl[512], ro[512];
  __shared__ int cnt[128], sc[128];
  __shared__ int stage[CAP];
  int b = blockIdx.x, t = threadIdx.x;
  for (int c = t; c < 512; c += 256) {
    int s0 = 0, len = 0;
    if (c < nchunks) {
      const int* rr = runs + (size_t)c * RSTRIDE;
      s0 = rr[b];
      len = rr[b + 1] - s0;
    }
    rs[c] = s0; rl[c] = len;
  }
  if (t < 128) cnt[t] = 0;
  __syncthreads();
  // exclusive scan rl -> ro (512 slots)
  ro[t] = rl[t]; ro[t + 256] = rl[t + 256];
  __syncthreads();
  for (int o = 1; o < 512; o <<= 1) {
    int v0 = (t >= o) ? ro[t - o] : 0;
    int v1 = (t + 256 >= o) ? ro[t + 256 - o] : 0;
    __syncthreads();
    ro[t] += v0; ro[t + 256] += v1;
    __syncthreads();
  }
  int ce = ro[511];
  int y0 = ro[t] - rl[t];
  int y1 = ro[t + 256] - rl[t + 256];
  __syncthreads();
  ro[t] = y0; ro[t + 256] = y1;
  __syncthreads();
  int colbase = b * CAP;
  bool fits = ce <= CAP;
  if (fits) {
    for (int c = t; c < nchunks; c += 256) {
      int gs = c * CHUNK + rs[c];
      int base = ro[c];
      int len = rl[c];
      for (int j = 0; j < len; ++j) {
        int p = pairs[gs + j];
        stage[base + j] = p;
        atomicAdd(&cnt[((unsigned)p) >> 24], 1);
      }
    }
  } else {  // statistically unreachable guard
    for (int c = t; c < nchunks; c += 256) {
      int gs = c * CHUNK + rs[c];
      for (int j = 0; j < rl[c]; ++j)
        atomicAdd(&cnt[((unsigned)pairs[gs + j]) >> 24], 1);
    }
  }
  __syncthreads();
  int v = 0, excl = 0;
  if (t < 128) { v = cnt[t]; sc[t] = v; }
  __syncthreads();
  for (int o = 1; o < 128; o <<= 1) {
    int x = (t >= o && t < 128) ? sc[t - o] : 0;
    __syncthreads();
    if (t < 128) sc[t] += x;
    __syncthreads();
  }
  if (t < 128) {
    excl = sc[t] - v;
    int node = b * 128 + t;
    if (node < N) {
      row_se[node] = make_int2(colbase + excl, colbase + excl + v);
      dis[node] = rsqrtf((float)(v + 1));  // +1 self-loop
    }
    cnt[t] = excl;  // reuse as cursor
  }
  __syncthreads();
  if (fits) {
    for (int j = t; j < ce; j += 256) {
      int p = stage[j];
      int loc = atomicAdd(&cnt[((unsigned)p) >> 24], 1);
      col[colbase + loc] = (p & 0xFFFFFF) << 8;  // byte offset: src * 256
    }
  } else {
    for (int c = t; c < nchunks; c += 256) {
      int gs = c * CHUNK + rs[c];
      for (int j = 0; j < rl[c]; ++j) {
        int p = pairs[gs + j];
        int loc = atomicAdd(&cnt[((unsigned)p) >> 24], 1);
        if (loc < CAP) col[colbase + loc] = (p & 0xFFFFFF) << 8;
      }
    }
  }
}

// ---------------- dense / fused kernels ----------------

// h1 = (X @ W1) * dis[row], fp32 in, fp16 out. MFMA swapped-operand form:
// D = W^T (A-op, m=feature) x X^T (B-op, n=node); lane stores 4 consecutive
// features of one node per tile.
__global__ __launch_bounds__(256) void mm1_kernel(
    const float* __restrict__ Av, const _Float16* __restrict__ Wpk,
    const float* __restrict__ scale, __half* __restrict__ C, int N) {
  int t = threadIdx.x;
  int wave = t >> 6, lane = t & 63;
  int quad = lane >> 4, nidx = lane & 15;
  int m0 = blockIdx.x * 64 + wave * 16;
  int arow = m0 + nidx;
  bool avalid = arow < N;
  floatx4 acc[8];
#pragma unroll
  for (int tn = 0; tn < 8; ++tn) acc[tn] = (floatx4){0.f, 0.f, 0.f, 0.f};
#pragma unroll
  for (int ks = 0; ks < 4; ++ks) {
    half8 x = {};
    if (avalid) {
      const float* p = Av + (size_t)arow * 128 + ks * 32 + quad * 8;
      float4 f0 = *(const float4*)p;
      float4 f1 = *(const float4*)(p + 4);
      x[0] = (_Float16)f0.x; x[1] = (_Float16)f0.y;
      x[2] = (_Float16)f0.z; x[3] = (_Float16)f0.w;
      x[4] = (_Float16)f1.x; x[5] = (_Float16)f1.y;
      x[6] = (_Float16)f1.z; x[7] = (_Float16)f1.w;
    }
#pragma unroll
    for (int tn = 0; tn < 8; ++tn) {
      half8 wfrag = *(const half8*)(Wpk + ((size_t)((tn * 4 + ks) * 64 + lane)) * 8);
      acc[tn] = __builtin_amdgcn_mfma_f32_16x16x32_f16(wfrag, x, acc[tn], 0, 0, 0);
    }
  }
  if (avalid) {
    float s = scale[arow];
#pragma unroll
    for (int tn = 0; tn < 8; ++tn) {
      union { uint2 u; __half2 h[2]; } st;
      st.h[0] = __floats2half2_rn(acc[tn][0] * s, acc[tn][1] * s);
      st.h[1] = __floats2half2_rn(acc[tn][2] * s, acc[tn][3] * s);
      *(uint2*)(C + (size_t)arow * 128 + tn * 16 + quad * 4) = st.u;
    }
  }
}

// Fused layer kernel (round-10 structure + dynamic load balancing):
// block owns 16 nodes; waves POP node indices from an LDS cursor (greedy
// balancing of gather time across waves), stage relu'd rows in LDS, barrier,
// then next-layer MFMA amortized across the block (wave = 2 feature-tiles).
__global__ __launch_bounds__(256) void agg_fuse_kernel(
    const __half* __restrict__ hs_in, const int2* __restrict__ row_se,
    const int* __restrict__ col, const float* __restrict__ dis,
    const float* __restrict__ bias, const _Float16* __restrict__ Wpk,
    __half* __restrict__ hs_out, int N) {
  __shared__ _Float16 Xs[16][136];  // pad 136: <=2-way LDS banks both phases
  __shared__ int next;
  int t = threadIdx.x;
  int wave = t >> 6, lane = t & 63;
  int n0 = blockIdx.x * 16;
  if (t == 0) next = 0;
  __syncthreads();
  const char* hb = (const char*)hs_in + lane * 4;  // lane's half2 within a row
  float2 b2 = ((const float2*)bias)[lane];
  for (;;) {
    int nl;
    if (lane == 0) nl = atomicAdd(&next, 1);
    nl = __shfl(nl, 0);
    if (nl >= 16) break;
    int node = n0 + nl;
    float ox = 0.f, oy = 0.f;
    if (node < N) {
      float2 selfv = __half22float2(*(const __half2*)(hb + ((size_t)node << 8)));
      float ax = selfv.x, ay = selfv.y;
      int2 se = row_se[node];
      int i = se.x, e = se.y;
      for (; i + 16 <= e; i += 16) {
        float2 v[16];
#pragma unroll
        for (int u = 0; u < 16; ++u)
          v[u] = __half22float2(*(const __half2*)(hb + col[i + u]));
        float bx = 0.f, by = 0.f;
#pragma unroll
        for (int u = 0; u < 16; ++u) { bx += v[u].x; by += v[u].y; }
        ax += bx; ay += by;
      }
      for (; i + 4 <= e; i += 4) {
        float2 v0 = __half22float2(*(const __half2*)(hb + col[i + 0]));
        float2 v1 = __half22float2(*(const __half2*)(hb + col[i + 1]));
        float2 v2 = __half22float2(*(const __half2*)(hb + col[i + 2]));
        float2 v3 = __half22float2(*(const __half2*)(hb + col[i + 3]));
        ax += (v0.x + v1.x) + (v2.x + v3.x);
        ay += (v0.y + v1.y) + (v2.y + v3.y);
      }
      for (; i < e; ++i) {
        float2 v = __half22float2(*(const __half2*)(hb + col[i]));
        ax += v.x; ay += v.y;
      }
      float d = dis[node];
      ox = fmaxf(fmaf(d, ax, b2.x), 0.f);
      oy = fmaxf(fmaf(d, ay, b2.y), 0.f);
    }
    *(__half2*)&Xs[nl][2 * lane] = __floats2half2_rn(ox, oy);
  }
  __syncthreads();
  int quad = lane >> 4, nidx = lane & 15;
  floatx4 acc0 = (floatx4){0.f, 0.f, 0.f, 0.f};
  floatx4 acc1 = (floatx4){0.f, 0.f, 0.f, 0.f};
  int tn0 = wave * 2;
#pragma unroll
  for (int ks = 0; ks < 4; ++ks) {
    half8 x = *(const half8*)&Xs[nidx][ks * 32 + quad * 8];
    half8 w0 = *(const half8*)(Wpk + ((size_t)((tn0 * 4 + ks) * 64 + lane)) * 8);
    half8 w1 = *(const half8*)(Wpk + ((size_t)(((tn0 + 1) * 4 + ks) * 64 + lane)) * 8);
    acc0 = __builtin_amdgcn_mfma_f32_16x16x32_f16(w0, x, acc0, 0, 0, 0);
    acc1 = __builtin_amdgcn_mfma_f32_16x16x32_f16(w1, x, acc1, 0, 0, 0);
  }
  int node = n0 + nidx;
  if (node < N) {
    float sc = dis[node];
    union { uint2 u; __half2 h[2]; } st;
    st.h[0] = __floats2half2_rn(acc0[0] * sc, acc0[1] * sc);
    st.h[1] = __floats2half2_rn(acc0[2] * sc, acc0[3] * sc);
    *(uint2*)(hs_out + (size_t)node * 128 + tn0 * 16 + quad * 4) = st.u;
    st.h[0] = __floats2half2_rn(acc1[0] * sc, acc1[1] * sc);
    st.h[1] = __floats2half2_rn(acc1[2] * sc, acc1[3] * sc);
    *(uint2*)(hs_out + (size_t)node * 128 + (tn0 + 1) * 16 + quad * 4) = st.u;
  }
}

// Standalone layer-3 aggregation (no following matmul).
__global__ __launch_bounds__(256) void agg_kernel(
    const __half* __restrict__ hs, const int2* __restrict__ row_se,
    const int* __restrict__ col, const float* __restrict__ dis,
    const float* __restrict__ bias, __half* __restrict__ out, int N) {
  int node = blockIdx.x * 4 + (threadIdx.x >> 6);
  int lane = threadIdx.x & 63;
  if (node >= N) return;
  const char* hb = (const char*)hs + lane * 4;
  float2 selfv = __half22float2(*(const __half2*)(hb + ((size_t)node << 8)));
  float ax = selfv.x, ay = selfv.y;
  int2 se = row_se[node];
  int i = se.x, e = se.y;
  for (; i + 16 <= e; i += 16) {
    float2 v[16];
#pragma unroll
    for (int u = 0; u < 16; ++u) v[u] = __half22float2(*(const __half2*)(hb + col[i + u]));
    float bx = 0.f, by = 0.f;
#pragma unroll
    for (int u = 0; u < 16; ++u) { bx += v[u].x; by += v[u].y; }
    ax += bx; ay += by;
  }
  for (; i + 4 <= e; i += 4) {
    float2 v0 = __half22float2(*(const __half2*)(hb + col[i + 0]));
    float2 v1 = __half22float2(*(const __half2*)(hb + col[i + 1]));
    float2 v2 = __half22float2(*(const __half2*)(hb + col[i + 2]));
    float2 v3 = __half22float2(*(const __half2*)(hb + col[i + 3]));
    ax += (v0.x + v1.x) + (v2.x + v3.x);
    ay += (v0.y + v1.y) + (v2.y + v3.y);
  }
  for (; i < e; ++i) {
    float2 v = __half22float2(*(const __half2*)(hb + col[i]));
    ax += v.x; ay += v.y;
  }
  float d = dis[node];
  float2 b2 = ((const float2*)bias)[lane];
  float ox = fmaxf(fmaf(d, ax, b2.x), 0.f);
  float oy = fmaxf(fmaf(d, ay, b2.y), 0.f);
  ((__half2*)out)[(size_t)node * 64 + lane] = __floats2half2_rn(ox, oy);
}

// Fused head: mean pool (batch sorted -> binary search) + lin1+relu + lin2.
__global__ __launch_bounds__(128) void head_kernel(
    const __half* __restrict__ h, const int* __restrict__ batch,
    const float* __restrict__ l1w, const float* __restrict__ l1b,
    const float* __restrict__ l2w, const float* __restrict__ l2b,
    float* __restrict__ out, int N, int C) {
  __shared__ float row[128];
  __shared__ float row2[128];
  int grp = blockIdx.x, t = threadIdx.x;
  int lo = 0, hi = N;
  while (lo < hi) { int m = (lo + hi) >> 1; if (batch[m] < grp) lo = m + 1; else hi = m; }
  int start = lo;
  hi = N;
  while (lo < hi) { int m = (lo + hi) >> 1; if (batch[m] <= grp) lo = m + 1; else hi = m; }
  int end = lo;
  float a0 = 0.f, a1 = 0.f, a2 = 0.f, a3 = 0.f;
  int i = start;
  for (; i + 4 <= end; i += 4) {
    a0 += __half2float(h[(size_t)i * 128 + t]);
    a1 += __half2float(h[(size_t)(i + 1) * 128 + t]);
    a2 += __half2float(h[(size_t)(i + 2) * 128 + t]);
    a3 += __half2float(h[(size_t)(i + 3) * 128 + t]);
  }
  for (; i < end; ++i) a0 += __half2float(h[(size_t)i * 128 + t]);
  float sum = (a0 + a1) + (a2 + a3);
  float cntf = (float)(end - start);
  row[t] = sum / fmaxf(cntf, 1.0f);
  __syncthreads();
  float acc = l1b[t];
#pragma unroll 8
  for (int k = 0; k < 128; ++k) acc = fmaf(row[k], l1w[k * 128 + t], acc);
  row2[t] = fmaxf(acc, 0.f);
  __syncthreads();
  if (t < C) {
    float a = l2b[t];
#pragma unroll 8
    for (int k = 0; k < 128; ++k) a = fmaf(row2[k], l2w[k * C + t], a);
    out[grp * C + t] = a;
  }
}

// ---------------- launch ----------------

extern "C" void kernel_launch(void* const* d_in, const int* in_sizes, int n_in,
                              void* d_out, int out_size, void* d_ws, size_t ws_size,
                              hipStream_t stream) {
  const float* x   = (const float*)d_in[0];
  const int*   ei  = (const int*)d_in[1];     // [2][E]: src row then dst row
  const int*   bat = (const int*)d_in[2];
  const float* W1  = (const float*)d_in[3];
  const float* b1  = (const float*)d_in[4];
  const float* W2  = (const float*)d_in[5];
  const float* b2  = (const float*)d_in[6];
  const float* W3  = (const float*)d_in[7];
  const float* b3  = (const float*)d_in[8];
  const float* l1w = (const float*)d_in[9];
  const float* l1b = (const float*)d_in[10];
  const float* l2w = (const float*)d_in[11];
  const float* l2b = (const float*)d_in[12];

  int N = in_sizes[2];
  int E = in_sizes[1] / 2;
  int C = in_sizes[12];
  int G = out_size / C;
  float* outp = (float*)d_out;

  char* wp = (char*)d_ws;
  auto alloc = [&](size_t bytes) -> void* {
    void* p = (void*)wp;
    wp += (bytes + 255) & ~(size_t)255;
    return p;
  };
  int nbuk    = (N + 127) / 128;            // 128-node buckets (<=1024)
  int nchunks = (E + CHUNK - 1) / CHUNK;    // sort chunks (<=512)

  float*    dis    = (float*)alloc((size_t)N * 4);
  int2*     row_se = (int2*)alloc((size_t)N * 8);
  int*      col    = (int*)alloc((size_t)nbuk * CAP * 4);
  int*      pairs  = (int*)alloc((size_t)nchunks * CHUNK * 4);
  int*      runs   = (int*)alloc((size_t)nchunks * RSTRIDE * 4);
  _Float16* Wpk1   = (_Float16*)alloc(16384 * 2);
  _Float16* Wpk2   = (_Float16*)alloc(16384 * 2);
  _Float16* Wpk3   = (_Float16*)alloc(16384 * 2);
  __half*   bufA   = (__half*)alloc((size_t)N * FEAT * 2);
  __half*   bufB   = (__half*)alloc((size_t)N * FEAT * 2);

  // CSR build (2 dispatches) + weight pre-pack (fused into the first)
  sort_prep_kernel<<<nchunks + 24, 256, 0, stream>>>(
      ei, E, nchunks, nbuk, pairs, runs, W1, W2, W3, Wpk1, Wpk2, Wpk3);
  bucket_csr_kernel<<<nbuk, 256, 0, stream>>>(pairs, runs, nchunks, nbuk,
                                              row_se, dis, col, N);

  int mmB = (N + 63) / 64;
  int fB  = (N + 15) / 16;
  int agB = (N + 3) / 4;

  mm1_kernel<<<mmB, 256, 0, stream>>>(x, Wpk1, dis, bufA, N);
  agg_fuse_kernel<<<fB, 256, 0, stream>>>(bufA, row_se, col, dis, b1,
                                          Wpk2, bufB, N);
  agg_fuse_kernel<<<fB, 256, 0, stream>>>(bufB, row_se, col, dis, b2,
                                          Wpk3, bufA, N);
  agg_kernel<<<agB, 256, 0, stream>>>(bufA, row_se, col, dis, b3, bufB, N);
  head_kernel<<<G, 128, 0, stream>>>(bufB, bat, l1w, l1b, l2w, l2b, outp, N, C);
}